// Round 1
// baseline (66.878 us; speedup 1.0000x reference)
//
#include <hip/hip_runtime.h>

// out[b,o] = x@W1 + x^T W2[:,:,o] x + bias
// Quadratic part as GEMM: T = X(512x784) @ W2v(784x7840), W2v = W+7840 row-major,
// then quad[b,o] = sum_j x[b,j] * T[b, j*10+o]  (fused into GEMM epilogue).

#define D_IN 784
#define N_COL 7840
#define KP 832          // K padded to multiple of 64 (832 = 13*64)
#define M_B 512
#define OUTN 10

typedef __attribute__((ext_vector_type(4))) float f32x4;
typedef __attribute__((ext_vector_type(8))) __bf16 bf16x8;

// round-to-nearest-even f32 -> bf16 (bit twiddle; inputs finite)
__device__ __forceinline__ unsigned short f2bf(float f) {
  unsigned u = __builtin_bit_cast(unsigned, f);
  u += 0x7FFFu + ((u >> 16) & 1u);
  return (unsigned short)(u >> 16);
}

// ---- prep: x (512x784 f32) -> xb (512x832 bf16, zero-padded K) ----
__global__ __launch_bounds__(256) void conv_x_kernel(const float* __restrict__ x,
                                                     unsigned short* __restrict__ xb) {
  int t = blockIdx.x * 256 + threadIdx.x;     // 512*208 threads, 4 bf16 each
  int b = t / 208;
  int c4 = (t - b * 208) * 4;
  ushort4 u;
  u.x = (c4 + 0 < D_IN) ? f2bf(x[(size_t)b * D_IN + c4 + 0]) : (unsigned short)0;
  u.y = (c4 + 1 < D_IN) ? f2bf(x[(size_t)b * D_IN + c4 + 1]) : (unsigned short)0;
  u.z = (c4 + 2 < D_IN) ? f2bf(x[(size_t)b * D_IN + c4 + 2]) : (unsigned short)0;
  u.w = (c4 + 3 < D_IN) ? f2bf(x[(size_t)b * D_IN + c4 + 3]) : (unsigned short)0;
  *(ushort4*)(xb + (size_t)b * KP + c4) = u;
}

// ---- prep: W2v (784x7840 f32, row-major) -> Wt (7840x832 bf16) transposed ----
// Wt[c][k] = W2v[k][c]; k >= 784 zero-padded. Both sides coalesced via LDS tile.
__global__ __launch_bounds__(256) void transpose_w_kernel(const float* __restrict__ W2v,
                                                          unsigned short* __restrict__ Wt) {
  __shared__ float tile[32][33];
  int c0 = blockIdx.x * 32;                   // 245 tiles
  int k0 = blockIdx.y * 32;                   // 26 tiles (covers 832)
  int tx = threadIdx.x;                       // 32
  int ty = threadIdx.y;                       // 8
#pragma unroll
  for (int q = 0; q < 4; ++q) {
    int ky = ty + 8 * q;
    int k = k0 + ky;
    tile[ky][tx] = (k < D_IN) ? W2v[(size_t)k * N_COL + (c0 + tx)] : 0.f;
  }
  __syncthreads();
#pragma unroll
  for (int q = 0; q < 4; ++q) {
    int cy = ty + 8 * q;
    Wt[(size_t)(c0 + cy) * KP + (k0 + tx)] = f2bf(tile[tx][cy]);
  }
}

// ---- linear part + bias: out[b,:] = x[b,:] @ W1 + bias  (overwrites poisoned out) ----
__global__ __launch_bounds__(256) void init_out_kernel(const float* __restrict__ x,
                                                       const float* __restrict__ W,
                                                       const float* __restrict__ bias,
                                                       float* __restrict__ out) {
  int b = blockIdx.x;
  int t = threadIdx.x;
  __shared__ float part[OUTN];
  if (t < OUTN) part[t] = bias[t];
  __syncthreads();
  float acc[OUTN];
#pragma unroll
  for (int o = 0; o < OUTN; ++o) acc[o] = 0.f;
  for (int i = t; i < D_IN; i += 256) {
    float xv = x[(size_t)b * D_IN + i];
#pragma unroll
    for (int o = 0; o < OUTN; ++o) acc[o] += xv * W[i * OUTN + o];
  }
#pragma unroll
  for (int o = 0; o < OUTN; ++o) {
    float v = acc[o];
#pragma unroll
    for (int s = 32; s > 0; s >>= 1) v += __shfl_down(v, s);
    if ((t & 63) == 0) atomicAdd(&part[o], v);
  }
  __syncthreads();
  if (t < OUTN) out[(size_t)b * OUTN + t] = part[t];
}

// ---- main: bf16 MFMA GEMM tile (64x80, BK=64) + fused quad reduction ----
// A = xb[512][832] (K-contig), B = Wt[7840][832] (K-contig, i.e. B^T form).
// 2 waves, each 32 rows x 80 cols -> acc[2][5] 16x16 frags.
// LDS XOR swizzle (byte ^= (row&7)<<4) kills the stride-128B bank conflict.
__global__ __launch_bounds__(128) void gemm_quad_kernel(const unsigned short* __restrict__ xb,
                                                        const unsigned short* __restrict__ Wt,
                                                        const float* __restrict__ x,
                                                        float* __restrict__ out) {
  __shared__ uint4 As4[512];                  // 64 rows x 128 B = 8 KB
  __shared__ uint4 Bs4[640];                  // 80 rows x 128 B = 10 KB
  const int tid = threadIdx.x;
  const int w = tid >> 6, l = tid & 63;
  const int lr = l & 15, lh = l >> 4;
  const int bn0 = blockIdx.x * 80;            // 98 col-tiles
  const int bm0 = blockIdx.y * 64;            // 8 row-tiles

  f32x4 acc[2][5];
#pragma unroll
  for (int mt = 0; mt < 2; ++mt)
#pragma unroll
    for (int nt = 0; nt < 5; ++nt) acc[mt][nt] = (f32x4){0.f, 0.f, 0.f, 0.f};

  for (int kt = 0; kt < KP / 64; ++kt) {
    // stage A tile: 512 x 16B chunks
#pragma unroll
    for (int q = 0; q < 4; ++q) {
      int idx = q * 128 + tid;
      int row = idx >> 3, k16 = idx & 7;
      uint4 v = *(const uint4*)(xb + (size_t)(bm0 + row) * KP + kt * 64 + k16 * 8);
      int byte = row * 128 + ((k16 * 16) ^ ((row & 7) << 4));
      *(uint4*)((char*)As4 + byte) = v;
    }
    // stage B tile: 640 x 16B chunks
#pragma unroll
    for (int q = 0; q < 5; ++q) {
      int idx = q * 128 + tid;
      int row = idx >> 3, k16 = idx & 7;
      uint4 v = *(const uint4*)(Wt + (size_t)(bn0 + row) * KP + kt * 64 + k16 * 8);
      int byte = row * 128 + ((k16 * 16) ^ ((row & 7) << 4));
      *(uint4*)((char*)Bs4 + byte) = v;
    }
    __syncthreads();
#pragma unroll
    for (int kk = 0; kk < 2; ++kk) {
      bf16x8 a[2], b[5];
#pragma unroll
      for (int mt = 0; mt < 2; ++mt) {
        int row = w * 32 + mt * 16 + lr;      // A frag: row = lane&15, k = 8*(lane>>4)+e
        int byte = row * 128 + (((kk * 64) + lh * 16) ^ ((row & 7) << 4));
        a[mt] = *(const bf16x8*)((char*)As4 + byte);
      }
#pragma unroll
      for (int nt = 0; nt < 5; ++nt) {
        int col = nt * 16 + lr;               // B frag: col = lane&15, k = 8*(lane>>4)+e
        int byte = col * 128 + (((kk * 64) + lh * 16) ^ ((col & 7) << 4));
        b[nt] = *(const bf16x8*)((char*)Bs4 + byte);
      }
#pragma unroll
      for (int mt = 0; mt < 2; ++mt)
#pragma unroll
        for (int nt = 0; nt < 5; ++nt)
          acc[mt][nt] = __builtin_amdgcn_mfma_f32_16x16x32_bf16(a[mt], b[nt], acc[mt][nt], 0, 0, 0);
    }
    __syncthreads();
  }

  // fused epilogue: quad[b,o] += sum over this block's 80 cols of x[b, c/10] * T[b, c]
  float* part = (float*)As4;                  // reuse A LDS: part[64][10]
  for (int i = tid; i < 64 * OUTN; i += 128) part[i] = 0.f;
  __syncthreads();
#pragma unroll
  for (int mt = 0; mt < 2; ++mt) {
    int rowB = w * 32 + mt * 16 + lh * 4;     // C/D: col = lane&15, row = (lane>>4)*4 + reg
#pragma unroll
    for (int nt = 0; nt < 5; ++nt) {
      int gc = bn0 + nt * 16 + lr;
      int j = gc / 10;
      int o = gc - j * 10;
#pragma unroll
      for (int r = 0; r < 4; ++r) {
        int rr = rowB + r;
        float xv = x[(size_t)(bm0 + rr) * D_IN + j];
        atomicAdd(&part[rr * OUTN + o], acc[mt][nt][r] * xv);
      }
    }
  }
  __syncthreads();
  for (int i = tid; i < 64 * OUTN; i += 128) {
    int rr = i / OUTN, o = i - (i / OUTN) * OUTN;
    atomicAdd(&out[(size_t)(bm0 + rr) * OUTN + o], part[i]);
  }
}

extern "C" void kernel_launch(void* const* d_in, const int* in_sizes, int n_in,
                              void* d_out, int out_size, void* d_ws, size_t ws_size,
                              hipStream_t stream) {
  const float* x = (const float*)d_in[0];     // 512 x 784
  const float* W = (const float*)d_in[1];     // 615440 x 10
  const float* bias = (const float*)d_in[2];  // 10
  float* out = (float*)d_out;                 // 512 x 10 f32

  unsigned short* xb = (unsigned short*)d_ws;            // 512*832 bf16 = 0.85 MB
  unsigned short* Wt = xb + (size_t)M_B * KP;            // 7840*832 bf16 = 13.0 MB

  conv_x_kernel<<<(M_B * (KP / 4)) / 256, 256, 0, stream>>>(x, xb);
  transpose_w_kernel<<<dim3(N_COL / 32, KP / 32), dim3(32, 8), 0, stream>>>(W + D_IN * OUTN, Wt);
  init_out_kernel<<<M_B, 256, 0, stream>>>(x, W, bias, out);
  gemm_quad_kernel<<<dim3(N_COL / 80, M_B / 64), 128, 0, stream>>>(xb, Wt, x, out);
}